// Round 1
// baseline (658.476 us; speedup 1.0000x reference)
//
#include <hip/hip_runtime.h>
#include <hip/hip_bf16.h>

// Problem constants (from reference)
#define NPTS   100000
#define NCENT  50000
#define NEDGE  1600000
#define DF     64      // feature dim
#define DP     3       // pos dim
#define DH     128     // hidden
#define DOUT   128     // out
#define K1PAD  96      // D+P=67 padded to 3*32 for K-steps
#define TILE   128     // edges per block
#define LDA    104     // A-tile leading dim (ushorts), 96 + 8 pad
#define LDH    136     // H1-tile leading dim (ushorts), 128 + 8 pad

typedef __attribute__((ext_vector_type(8))) short short8;
typedef __attribute__((ext_vector_type(4))) float f32x4;

__device__ __forceinline__ unsigned short f2bf(float f) {
  union { __hip_bfloat16 h; unsigned short u; } v;
  v.h = __float2bfloat16(f);
  return v.u;
}

// Order-preserving float->uint encoding: uint compare == float compare.
// key==0 is below every encodable real value -> serves as "-inf / untouched".
__device__ __forceinline__ unsigned encodeKey(float f) {
  unsigned u = __float_as_uint(f);
  return u ^ ((unsigned)((int)u >> 31) | 0x80000000u);
}

__device__ __forceinline__ float decodeKey(unsigned k) {
  if (k == 0u) return 0.0f;  // empty segment -> 0 (torch_scatter convention)
  unsigned u = (k & 0x80000000u) ? (k ^ 0x80000000u) : ~k;
  return __uint_as_float(u);
}

// Pack W1 [67x128] f32 -> bf16 B-fragments, zero-padded K to 96.
// Fragment order: frag[nt][ks][lane][j], n = nt*16+(lane&15), k = ks*32+(lane>>4)*8+j
__global__ void k_pack_w1(const float* __restrict__ W1, unsigned short* __restrict__ W1f) {
  int tid = blockIdx.x * blockDim.x + threadIdx.x;  // 0..1535 (8 nt * 3 ks * 64 lanes)
  int lane = tid & 63, g = tid >> 6;
  int nt = g / 3, ks = g % 3;
  int n = nt * 16 + (lane & 15);
  int k0 = ks * 32 + (lane >> 4) * 8;
  short8 v;
  for (int j = 0; j < 8; ++j) {
    int k = k0 + j;
    float f = (k < DF + DP) ? W1[k * DH + n] : 0.0f;
    v[j] = (short)f2bf(f);
  }
  *reinterpret_cast<short8*>(W1f + (size_t)tid * 8) = v;
}

// Pack W2 [128x128] f32 -> bf16 B-fragments. frag[nt][ks][lane][j], ks in 0..3
__global__ void k_pack_w2(const float* __restrict__ W2, unsigned short* __restrict__ W2f) {
  int tid = blockIdx.x * blockDim.x + threadIdx.x;  // 0..2047 (8 nt * 4 ks * 64 lanes)
  int lane = tid & 63, g = tid >> 6;
  int nt = g >> 2, ks = g & 3;
  int n = nt * 16 + (lane & 15);
  int k0 = ks * 32 + (lane >> 4) * 8;
  short8 v;
  for (int j = 0; j < 8; ++j) {
    int k = k0 + j;
    v[j] = (short)f2bf(W2[k * DH + n]);
  }
  *reinterpret_cast<short8*>(W2f + (size_t)tid * 8) = v;
}

__global__ void k_init(unsigned* __restrict__ out) {
  int i = blockIdx.x * blockDim.x + threadIdx.x;
  reinterpret_cast<uint4*>(out)[i] = make_uint4(0u, 0u, 0u, 0u);
}

__global__ void k_decode(unsigned* __restrict__ out) {
  int i = blockIdx.x * blockDim.x + threadIdx.x;
  uint4 v = reinterpret_cast<uint4*>(out)[i];
  float4 f;
  f.x = decodeKey(v.x);
  f.y = decodeKey(v.y);
  f.z = decodeKey(v.z);
  f.w = decodeKey(v.w);
  reinterpret_cast<float4*>(out)[i] = f;
}

// Fused: gather feats -> GEMM1(relu) -> GEMM2 -> atomicMax scatter.
// 256 threads = 4 waves; 128-edge tile; wave w owns edge rows [32w, 32w+32).
__global__ void __launch_bounds__(256)
k_mlp(const float* __restrict__ x, const float* __restrict__ pos,
      const float* __restrict__ pos_c, const int* __restrict__ src,
      const int* __restrict__ dst, const float* __restrict__ b1,
      const float* __restrict__ b2, const unsigned short* __restrict__ W1f,
      const unsigned short* __restrict__ W2f, unsigned* __restrict__ outU) {
  __shared__ __align__(16) unsigned short Atile[TILE * LDA];   // 26624 B
  __shared__ __align__(16) unsigned short H1s[TILE * LDH];     // 34816 B
  __shared__ int dstLoc[TILE];

  const int t = threadIdx.x;
  const int e0 = blockIdx.x * TILE;

  // ---- Stage A-tile: [128 edges] x [96 k] bf16 (cols 0..63 = x[src], 64..66 = pos diff, 67..95 = 0)
  {
    const int e = t >> 1, p = t & 1;
    const int s = src[e0 + e];
    const float4* xr = reinterpret_cast<const float4*>(x + (size_t)s * DF);
    for (int i = 0; i < 4; ++i) {
      float4 v0 = xr[p * 8 + 2 * i];
      float4 v1 = xr[p * 8 + 2 * i + 1];
      short8 w;
      w[0] = (short)f2bf(v0.x); w[1] = (short)f2bf(v0.y);
      w[2] = (short)f2bf(v0.z); w[3] = (short)f2bf(v0.w);
      w[4] = (short)f2bf(v1.x); w[5] = (short)f2bf(v1.y);
      w[6] = (short)f2bf(v1.z); w[7] = (short)f2bf(v1.w);
      *reinterpret_cast<short8*>(&Atile[e * LDA + p * 32 + i * 8]) = w;
    }
    // zero cols 72..103 (covers K-pad; cols 64..71 written by pos pack below)
    short8 z = {0, 0, 0, 0, 0, 0, 0, 0};
    *reinterpret_cast<short8*>(&Atile[e * LDA + 72 + p * 16]) = z;
    *reinterpret_cast<short8*>(&Atile[e * LDA + 72 + p * 16 + 8]) = z;
  }
  if (t < TILE) {
    const int e = t;
    const int s = src[e0 + e];
    const int c = dst[e0 + e];
    dstLoc[e] = c;
    float dx = pos[(size_t)s * 3 + 0] - pos_c[(size_t)c * 3 + 0];
    float dy = pos[(size_t)s * 3 + 1] - pos_c[(size_t)c * 3 + 1];
    float dz = pos[(size_t)s * 3 + 2] - pos_c[(size_t)c * 3 + 2];
    short8 w = {0, 0, 0, 0, 0, 0, 0, 0};
    w[0] = (short)f2bf(dx); w[1] = (short)f2bf(dy); w[2] = (short)f2bf(dz);
    *reinterpret_cast<short8*>(&Atile[e * LDA + 64]) = w;  // cols 64..71
  }
  __syncthreads();

  const int lane = t & 63;
  const int w = t >> 6;
  const int l16 = lane & 15;
  const int quad = lane >> 4;

  // ---- GEMM1: [128 x 96] @ [96 x 128] -> relu -> H1s (bf16)
  {
    short8 a[2][3];
    for (int mi = 0; mi < 2; ++mi) {
      int row = (2 * w + mi) * 16 + l16;
      for (int ks = 0; ks < 3; ++ks)
        a[mi][ks] = *reinterpret_cast<const short8*>(&Atile[row * LDA + ks * 32 + quad * 8]);
    }
    for (int nt = 0; nt < 8; ++nt) {
      short8 b[3];
      for (int ks = 0; ks < 3; ++ks)
        b[ks] = *reinterpret_cast<const short8*>(W1f + ((size_t)(nt * 3 + ks) * 64 + lane) * 8);
      f32x4 acc0 = {0.f, 0.f, 0.f, 0.f}, acc1 = {0.f, 0.f, 0.f, 0.f};
      for (int ks = 0; ks < 3; ++ks) {
        acc0 = __builtin_amdgcn_mfma_f32_16x16x32_bf16(a[0][ks], b[ks], acc0, 0, 0, 0);
        acc1 = __builtin_amdgcn_mfma_f32_16x16x32_bf16(a[1][ks], b[ks], acc1, 0, 0, 0);
      }
      int n = nt * 16 + l16;
      float bias = b1[n];
      for (int r = 0; r < 4; ++r) {
        float v0 = acc0[r] + bias; v0 = v0 > 0.f ? v0 : 0.f;
        H1s[((2 * w) * 16 + quad * 4 + r) * LDH + n] = f2bf(v0);
        float v1 = acc1[r] + bias; v1 = v1 > 0.f ? v1 : 0.f;
        H1s[((2 * w + 1) * 16 + quad * 4 + r) * LDH + n] = f2bf(v1);
      }
    }
  }
  __syncthreads();

  // ---- GEMM2: [128 x 128] @ [128 x 128] -> + b2 -> atomicMax scatter
  {
    short8 a[2][4];
    for (int mi = 0; mi < 2; ++mi) {
      int row = (2 * w + mi) * 16 + l16;
      for (int ks = 0; ks < 4; ++ks)
        a[mi][ks] = *reinterpret_cast<const short8*>(&H1s[row * LDH + ks * 32 + quad * 8]);
    }
    for (int nt = 0; nt < 8; ++nt) {
      short8 b[4];
      for (int ks = 0; ks < 4; ++ks)
        b[ks] = *reinterpret_cast<const short8*>(W2f + ((size_t)(nt * 4 + ks) * 64 + lane) * 8);
      f32x4 acc0 = {0.f, 0.f, 0.f, 0.f}, acc1 = {0.f, 0.f, 0.f, 0.f};
      for (int ks = 0; ks < 4; ++ks) {
        acc0 = __builtin_amdgcn_mfma_f32_16x16x32_bf16(a[0][ks], b[ks], acc0, 0, 0, 0);
        acc1 = __builtin_amdgcn_mfma_f32_16x16x32_bf16(a[1][ks], b[ks], acc1, 0, 0, 0);
      }
      int n = nt * 16 + l16;
      float bias = b2[n];
      for (int r = 0; r < 4; ++r) {
        {
          float v = acc0[r] + bias;
          int edge = (2 * w) * 16 + quad * 4 + r;
          unsigned key = encodeKey(v);
          atomicMax(&outU[(size_t)dstLoc[edge] * DOUT + n], key);
        }
        {
          float v = acc1[r] + bias;
          int edge = (2 * w + 1) * 16 + quad * 4 + r;
          unsigned key = encodeKey(v);
          atomicMax(&outU[(size_t)dstLoc[edge] * DOUT + n], key);
        }
      }
    }
  }
}

extern "C" void kernel_launch(void* const* d_in, const int* in_sizes, int n_in,
                              void* d_out, int out_size, void* d_ws, size_t ws_size,
                              hipStream_t stream) {
  const float* x     = (const float*)d_in[0];
  // d_in[1] = x_c: only shape used by reference
  const float* pos   = (const float*)d_in[2];
  const float* pos_c = (const float*)d_in[3];
  const int*   src   = (const int*)d_in[4];
  const int*   dst   = (const int*)d_in[5];
  const float* W1    = (const float*)d_in[6];
  const float* b1    = (const float*)d_in[7];
  const float* W2    = (const float*)d_in[8];
  const float* b2    = (const float*)d_in[9];
  unsigned* outU = (unsigned*)d_out;

  unsigned short* W1f = (unsigned short*)d_ws;          // 8*3*64*8 ushorts = 24 KB
  unsigned short* W2f = W1f + 8 * 3 * 64 * 8;           // 8*4*64*8 ushorts = 32 KB

  k_pack_w1<<<6, 256, 0, stream>>>(W1, W1f);
  k_pack_w2<<<8, 256, 0, stream>>>(W2, W2f);
  k_init<<<(NCENT * DOUT / 4) / 256, 256, 0, stream>>>(outU);
  k_mlp<<<NEDGE / TILE, 256, 0, stream>>>(x, pos, pos_c, src, dst, b1, b2, W1f, W2f, outU);
  k_decode<<<(NCENT * DOUT / 4) / 256, 256, 0, stream>>>(outU);
}